// Round 5
// baseline (785.441 us; speedup 1.0000x reference)
//
#include <hip/hip_runtime.h>

typedef _Float16 f16x8 __attribute__((ext_vector_type(8)));
typedef float f32x4 __attribute__((ext_vector_type(4)));
typedef unsigned short us4v __attribute__((ext_vector_type(4)));

__device__ inline unsigned short f16b(float v) {
    _Float16 h = (_Float16)v;
    return __builtin_bit_cast(unsigned short, h);
}

__device__ inline f16x8 cvt8(float4 a, float4 b) {
    f16x8 r;
    r[0] = (_Float16)a.x; r[1] = (_Float16)a.y; r[2] = (_Float16)a.z; r[3] = (_Float16)a.w;
    r[4] = (_Float16)b.x; r[5] = (_Float16)b.y; r[6] = (_Float16)b.z; r[7] = (_Float16)b.w;
    return r;
}

__device__ inline void atomAddF(float* p, float v) {
    __hip_atomic_fetch_add(p, v, __ATOMIC_RELAXED, __HIP_MEMORY_SCOPE_AGENT);
}

// P [2048][4096][2] f32  ->  PT [4096][4096] f16 where PT[m][n*2+p] = P[n][m][p]
__global__ __launch_bounds__(256) void transpose_p(const float* __restrict__ P,
                                                   unsigned short* __restrict__ PT) {
    __shared__ unsigned int lds[64][33];
    int bid = blockIdx.x;
    int m0 = (bid & 127) * 32;
    int n0 = (bid >> 7) * 64;
    int tid = threadIdx.x;
    const float2* P2 = (const float2*)P;
    #pragma unroll
    for (int it = 0; it < 8; ++it) {
        int idx = it * 256 + tid;
        int nl = idx >> 5, ml = idx & 31;
        float2 v = P2[(size_t)(n0 + nl) * 4096 + (m0 + ml)];
        unsigned int pk = (unsigned int)f16b(v.x) | ((unsigned int)f16b(v.y) << 16);
        lds[nl][ml] = pk;
    }
    __syncthreads();
    unsigned int* PTu = (unsigned int*)PT;
    #pragma unroll
    for (int it = 0; it < 8; ++it) {
        int idx = it * 256 + tid;
        int ml = idx >> 6, nl = idx & 63;
        PTu[(size_t)(m0 + ml) * 2048 + (n0 + nl)] = lds[nl][ml];
    }
}

// ---------------- per-layer B-matrix build, BN fused (fragment layout) ----------------
// Fragment layout: elem index ((t*2+h)*64+lane)*8+e holds B[k=t*32+(lane>>4)*8+e][g=h*16+(lane&15)]
__global__ __launch_bounds__(256) void build_b(
    const float* __restrict__ srcx, const float* __restrict__ srcy,
    int Fin, int Fout, int buildB2, int use_bn,
    const float* __restrict__ stats,
    const float* __restrict__ gx, const float* __restrict__ btx,
    const float* __restrict__ gy, const float* __restrict__ bty,
    const float* __restrict__ w1a, const float* __restrict__ w1b,
    const float* __restrict__ w2a, const float* __restrict__ w2b,
    unsigned short* __restrict__ B1f, unsigned short* __restrict__ B2f) {
    int tid0 = blockIdx.x * 256 + threadIdx.x;
    const int NB1 = 14336 * 32;
    int isB2 = 0, t2 = tid0;
    if (tid0 >= NB1) {
        if (!buildB2) return;
        isB2 = 1; t2 = tid0 - NB1;
        if (t2 >= 16384 * 32) return;
    }
    int e = t2 & 7, lane = (t2 >> 3) & 63, hh = (t2 >> 9) & 1, t = t2 >> 10;
    int k = (t << 5) | ((lane >> 4) << 3) | e;
    int g = (hh << 4) | (lane & 15);
    float v = 0.f;
    if (g < Fout) {
        const float* hr; const float* wc; int useY;
        if (!isB2) {
            if (k < 6144) { int m = k / 3, j = k - 3 * m; hr = srcx + m * Fin; wc = w1a + (j * Fin) * Fout + g; useY = 0; }
            else { int k2 = k - 6144; int m = k2 >> 1, p = k2 & 1; hr = srcy + m * Fin; wc = w1b + (p * Fin) * Fout + g; useY = 1; }
        } else {
            if (k < 12288) { int m = k / 3, j = k - 3 * m; hr = srcy + m * Fin; wc = w2a + (j * Fin) * Fout + g; useY = 1; }
            else { int k2 = k - 12288; int n = k2 >> 1, p = k2 & 1; hr = srcx + n * Fin; wc = w2b + (p * Fin) * Fout + g; useY = 0; }
        }
        float a = 0.f;
        if (use_bn) {
            const float* st = useY ? stats + 64 : stats;
            const float* gv = useY ? gy : gx;
            const float* bv = useY ? bty : btx;
            float invn = useY ? (1.f / 4096.f) : (1.f / 2048.f);
            #pragma unroll
            for (int f = 0; f < 32; ++f) {
                float mean = st[f] * invn;
                float var = st[32 + f] * invn - mean * mean;
                float sc = gv[f] * rsqrtf(var + 1e-5f);
                float h = sc * (hr[f] - mean) + bv[f];
                a += h * wc[f * Fout];
            }
        } else {
            for (int f = 0; f < Fin; ++f) a += hr[f] * wc[f * Fout];
        }
        v = a;
    }
    if (!isB2) B1f[t2] = f16b(v); else B2f[t2] = f16b(v);
}

// ---------------- split-K MFMA GEMM -> deterministic partials ----------------
// K-seg = 512 elems, 16 inner iters.
// x-branch: 16 mwgs (128 rows) x 28 ksegs = 448 WGs (segs 0..11 = W, 12..27 = P)
// y-branch: 32 mwgs x 32 ksegs = 1024 WGs (segs 0..23 = WL, 24..31 = PT)
// CVT=1 (layer 0): A read from fp32 originals, converted in-register, fp16 copy stored.
template<int CVT>
__global__ __launch_bounds__(256) void gemm_k(
    const float* __restrict__ Wf, const float* __restrict__ Pf, const float* __restrict__ WLf,
    const unsigned short* __restrict__ Wb, const unsigned short* __restrict__ Pb,
    const unsigned short* __restrict__ WLb, const unsigned short* __restrict__ PTb,
    unsigned short* __restrict__ Wbw, unsigned short* __restrict__ Pbw, unsigned short* __restrict__ WLbw,
    const unsigned short* __restrict__ B1f, const unsigned short* __restrict__ B2f,
    float* __restrict__ px, float* __restrict__ py, float* __restrict__ stats, int nwgx) {
    int bid = blockIdx.x;
    if (bid == 0 && threadIdx.x < 128) stats[threadIdx.x] = 0.f;  // pre-zero for next reduce
    const unsigned short* Bf;
    float* Z;
    int seg, Mbase, rowlen, kloc, kb, usef32 = 0;
    const unsigned short* A16; const float* A32; unsigned short* A16w;
    if (bid < nwgx) {
        Bf = B1f;
        int mwg = bid / 28; seg = bid % 28;
        Mbase = mwg * 128;
        kb = seg << 9;
        Z = px + (size_t)seg * 65536;
        if (seg < 12) { rowlen = 6144; kloc = kb;        A16 = Wb; A32 = Wf; A16w = Wbw; usef32 = CVT; }
        else          { rowlen = 8192; kloc = kb - 6144; A16 = Pb; A32 = Pf; A16w = Pbw; usef32 = CVT; }
    } else {
        int b2 = bid - nwgx;
        Bf = B2f;
        int mwg = b2 / 32; seg = b2 % 32;
        Mbase = mwg * 128;
        kb = seg << 9;
        Z = py + (size_t)seg * 131072;
        if (seg < 24) { rowlen = 12288; kloc = kb;         A16 = WLb; A32 = WLf; A16w = WLbw; usef32 = CVT; }
        else          { rowlen = 4096;  kloc = kb - 12288; A16 = PTb; A32 = nullptr; A16w = nullptr; usef32 = 0; }
    }
    int wid = threadIdx.x >> 6, lane = threadIdx.x & 63;
    int rowbase = Mbase + wid * 32;
    size_t eoff = (size_t)(rowbase + (lane & 15)) * rowlen + kloc + ((lane >> 4) << 3);
    size_t eoff1 = eoff + (size_t)16 * rowlen;
    const unsigned short* bp = Bf + ((size_t)(kb >> 5)) * 1024 + lane * 8;
    f32x4 acc00 = {0.f,0.f,0.f,0.f}, acc01 = {0.f,0.f,0.f,0.f};
    f32x4 acc10 = {0.f,0.f,0.f,0.f}, acc11 = {0.f,0.f,0.f,0.f};
    if (CVT && usef32) {
        const float4* f0 = (const float4*)(A32 + eoff);
        const float4* f1 = (const float4*)(A32 + eoff1);
        f16x8* w0 = (f16x8*)(A16w + eoff);
        f16x8* w1 = (f16x8*)(A16w + eoff1);
        #pragma unroll 4
        for (int ks = 0; ks < 16; ++ks) {
            f16x8 a0 = cvt8(f0[0], f0[1]);
            f16x8 a1 = cvt8(f1[0], f1[1]);
            *w0 = a0; *w1 = a1;
            f16x8 b0 = *(const f16x8*)bp;
            f16x8 b1 = *(const f16x8*)(bp + 512);
            acc00 = __builtin_amdgcn_mfma_f32_16x16x32_f16(a0, b0, acc00, 0, 0, 0);
            acc10 = __builtin_amdgcn_mfma_f32_16x16x32_f16(a1, b0, acc10, 0, 0, 0);
            acc01 = __builtin_amdgcn_mfma_f32_16x16x32_f16(a0, b1, acc01, 0, 0, 0);
            acc11 = __builtin_amdgcn_mfma_f32_16x16x32_f16(a1, b1, acc11, 0, 0, 0);
            f0 += 8; f1 += 8; w0 += 4; w1 += 4; bp += 1024;  // advance 32 elements/iter
        }
    } else {
        const unsigned short* ap0 = A16 + eoff;
        const unsigned short* ap1 = A16 + eoff1;
        #pragma unroll 4
        for (int ks = 0; ks < 16; ++ks) {
            f16x8 a0 = *(const f16x8*)ap0;
            f16x8 a1 = *(const f16x8*)ap1;
            f16x8 b0 = *(const f16x8*)bp;
            f16x8 b1 = *(const f16x8*)(bp + 512);
            acc00 = __builtin_amdgcn_mfma_f32_16x16x32_f16(a0, b0, acc00, 0, 0, 0);
            acc10 = __builtin_amdgcn_mfma_f32_16x16x32_f16(a1, b0, acc10, 0, 0, 0);
            acc01 = __builtin_amdgcn_mfma_f32_16x16x32_f16(a0, b1, acc01, 0, 0, 0);
            acc11 = __builtin_amdgcn_mfma_f32_16x16x32_f16(a1, b1, acc11, 0, 0, 0);
            ap0 += 32; ap1 += 32; bp += 1024;
        }
    }
    int col = lane & 15, r0 = (lane >> 4) << 2;
    float* z0 = Z + (size_t)(rowbase + r0) * 32 + col;
    #pragma unroll
    for (int r = 0; r < 4; ++r) {
        z0[(size_t)r * 32]             = acc00[r];
        z0[(size_t)r * 32 + 16]        = acc01[r];
        z0[(size_t)(r + 16) * 32]      = acc10[r];
        z0[(size_t)(r + 16) * 32 + 16] = acc11[r];
    }
}

// ---------------- reduce partials + bias + relu-half + column stats ----------------
// blocks 0..63: x (65536 elems), 64..191: y (131072 elems); each thread one float4
__global__ __launch_bounds__(256) void reduce_stats(
    const float* __restrict__ px, const float* __restrict__ py,
    const float* __restrict__ bx, const float* __restrict__ by,
    float* __restrict__ zax, float* __restrict__ zay,
    float* __restrict__ stats) {
    __shared__ float lsum[4][8][8];
    int bid = blockIdx.x, tid = threadIdx.x;
    const float4* src; const float* bias; float4* dst; float* st; int nseg, i4, stride4;
    if (bid < 64) { src = (const float4*)px; bias = bx; dst = (float4*)zax; st = stats;      nseg = 28; i4 = bid * 256 + tid;        stride4 = 16384; }
    else          { src = (const float4*)py; bias = by; dst = (float4*)zay; st = stats + 64; nseg = 32; i4 = (bid - 64) * 256 + tid; stride4 = 32768; }
    float4 s = {0.f, 0.f, 0.f, 0.f};
    for (int g = 0; g < nseg; ++g) {
        float4 v = src[(size_t)g * stride4 + i4];
        s.x += v.x; s.y += v.y; s.z += v.z; s.w += v.w;
    }
    int c0 = (i4 & 7) * 4;
    float4 b4 = *(const float4*)(bias + c0);
    s.x += b4.x; s.y += b4.y; s.z += b4.z; s.w += b4.w;
    if (c0 < 16) {
        s.x = fmaxf(s.x, 0.f); s.y = fmaxf(s.y, 0.f);
        s.z = fmaxf(s.z, 0.f); s.w = fmaxf(s.w, 0.f);
    }
    dst[i4] = s;
    float4 s2 = {s.x * s.x, s.y * s.y, s.z * s.z, s.w * s.w};
    #pragma unroll
    for (int mask = 8; mask <= 32; mask <<= 1) {
        s.x += __shfl_xor(s.x, mask); s.y += __shfl_xor(s.y, mask);
        s.z += __shfl_xor(s.z, mask); s.w += __shfl_xor(s.w, mask);
        s2.x += __shfl_xor(s2.x, mask); s2.y += __shfl_xor(s2.y, mask);
        s2.z += __shfl_xor(s2.z, mask); s2.w += __shfl_xor(s2.w, mask);
    }
    int w = tid >> 6, ln = tid & 63;
    if (ln < 8) {
        lsum[w][ln][0] = s.x;  lsum[w][ln][1] = s.y;  lsum[w][ln][2] = s.z;  lsum[w][ln][3] = s.w;
        lsum[w][ln][4] = s2.x; lsum[w][ln][5] = s2.y; lsum[w][ln][6] = s2.z; lsum[w][ln][7] = s2.w;
    }
    __syncthreads();
    if (tid < 64) {
        int q = tid >> 3, e = tid & 7;
        float v = lsum[0][q][e] + lsum[1][q][e] + lsum[2][q][e] + lsum[3][q][e];
        int col = q * 4 + (e & 3);
        atomAddF((e < 4) ? &st[col] : &st[32 + col], v);
    }
}

// ---------------- final: sum x-partials + bl -> out ----------------
__global__ __launch_bounds__(256) void out_final(const float* __restrict__ px,
                                                 const float* __restrict__ bl,
                                                 float* __restrict__ out) {
    int tid = blockIdx.x * 256 + threadIdx.x;
    if (tid < 4096) {
        int n = tid >> 1, c = tid & 1;
        float a = bl[c];
        for (int s = 0; s < 28; ++s) a += px[(size_t)s * 65536 + n * 32 + c];
        out[tid] = a;
    }
}

extern "C" void kernel_launch(void* const* d_in, const int* in_sizes, int n_in,
                              void* d_out, int out_size, void* d_ws, size_t ws_size,
                              hipStream_t stream) {
    const float* W    = (const float*)d_in[0];
    const float* x    = (const float*)d_in[1];
    const float* WL   = (const float*)d_in[2];
    const float* y    = (const float*)d_in[3];
    const float* P    = (const float*)d_in[4];
    const float* wx2x0 = (const float*)d_in[5];
    const float* wy2x0 = (const float*)d_in[6];
    const float* bx0   = (const float*)d_in[7];
    const float* wy2y0 = (const float*)d_in[8];
    const float* wx2y0 = (const float*)d_in[9];
    const float* by0   = (const float*)d_in[10];
    const float* gx0   = (const float*)d_in[11];
    const float* btx0  = (const float*)d_in[12];
    const float* gy0   = (const float*)d_in[13];
    const float* bty0  = (const float*)d_in[14];
    const float* wx2x_m = (const float*)d_in[15];
    const float* wy2x_m = (const float*)d_in[16];
    const float* bx_m   = (const float*)d_in[17];
    const float* wy2y_m = (const float*)d_in[18];
    const float* wx2y_m = (const float*)d_in[19];
    const float* by_m   = (const float*)d_in[20];
    const float* gx_m   = (const float*)d_in[21];
    const float* btx_m  = (const float*)d_in[22];
    const float* gy_m   = (const float*)d_in[23];
    const float* bty_m  = (const float*)d_in[24];
    const float* wlx = (const float*)d_in[25];
    const float* wly = (const float*)d_in[26];
    const float* bl  = (const float*)d_in[27];

    char* base = (char*)d_ws;
    unsigned short* Wb  = (unsigned short*)(base + 0);          // 25,165,824 B
    unsigned short* Pb  = (unsigned short*)(base + 25165824);   // 33,554,432 B
    unsigned short* WLb = (unsigned short*)(base + 58720256);   // 100,663,296 B
    unsigned short* PTb = (unsigned short*)(base + 159383552);  // 33,554,432 B
    unsigned short* B1f = (unsigned short*)(base + 192937984);  // 917,504 B
    unsigned short* B2f = (unsigned short*)(base + 193855488);  // 1,048,576 B
    float* zax   = (float*)(base + 194904064);  // 262,144 B
    float* zay   = (float*)(base + 195166208);  // 524,288 B
    float* stats = (float*)(base + 195690496);  // 512 B
    float* px    = (float*)(base + 195691008);  // 28*65536*4  = 7,340,032 B
    float* py    = (float*)(base + 203031040);  // 32*131072*4 = 16,777,216 B

    // PT must exist before gemm0 (y segs 24..31 read it)
    transpose_p<<<4096, 256, 0, stream>>>(P, PTb);

    // block 0 (Fin = 1, raw x/y, no bn); gemm0 converts fp32->fp16 in-flight
    build_b<<<3840, 256, 0, stream>>>(x, y, 1, 32, 1, 0, nullptr, nullptr, nullptr, nullptr, nullptr,
                                      wx2x0, wy2x0, wy2y0, wx2y0, B1f, B2f);
    gemm_k<1><<<1472, 256, 0, stream>>>(W, P, WL, Wb, Pb, WLb, PTb, Wb, Pb, WLb,
                                        B1f, B2f, px, py, stats, 448);
    reduce_stats<<<192, 256, 0, stream>>>(px, py, bx0, by0, zax, zay, stats);

    // blocks 1..6 (middle weights i = 0..5); bn params of block i come from previous block
    for (int i = 0; i < 6; ++i) {
        const float* gv  = (i == 0) ? gx0  : gx_m  + (i - 1) * 32;
        const float* bv  = (i == 0) ? btx0 : btx_m + (i - 1) * 32;
        const float* gvy = (i == 0) ? gy0  : gy_m  + (i - 1) * 32;
        const float* bvy = (i == 0) ? bty0 : bty_m + (i - 1) * 32;
        build_b<<<3840, 256, 0, stream>>>(zax, zay, 32, 32, 1, 1, stats, gv, bv, gvy, bvy,
                                          wx2x_m + i * 3072, wy2x_m + i * 2048,
                                          wy2y_m + i * 3072, wx2y_m + i * 2048, B1f, B2f);
        gemm_k<0><<<1472, 256, 0, stream>>>(nullptr, nullptr, nullptr, Wb, Pb, WLb, PTb,
                                            nullptr, nullptr, nullptr,
                                            B1f, B2f, px, py, stats, 448);
        reduce_stats<<<192, 256, 0, stream>>>(px, py, bx_m + i * 32, by_m + i * 32, zax, zay, stats);
    }

    // final layer: bn of block 6 (gx_m[5]...), linear weights, x-branch only
    build_b<<<1792, 256, 0, stream>>>(zax, zay, 32, 2, 0, 1, stats,
                                      gx_m + 5 * 32, btx_m + 5 * 32, gy_m + 5 * 32, bty_m + 5 * 32,
                                      wlx, wly, nullptr, nullptr, B1f, B2f);
    gemm_k<0><<<448, 256, 0, stream>>>(nullptr, nullptr, nullptr, Wb, Pb, WLb, PTb,
                                       nullptr, nullptr, nullptr,
                                       B1f, B2f, px, py, stats, 448);
    out_final<<<16, 256, 0, stream>>>(px, bl, (float*)d_out);
}

// Round 6
// 707.843 us; speedup vs baseline: 1.1096x; 1.1096x over previous
//
#include <hip/hip_runtime.h>

typedef _Float16 f16x8 __attribute__((ext_vector_type(8)));
typedef float f32x4 __attribute__((ext_vector_type(4)));
typedef unsigned short us4v __attribute__((ext_vector_type(4)));

__device__ inline unsigned short f16b(float v) {
    _Float16 h = (_Float16)v;
    return __builtin_bit_cast(unsigned short, h);
}

__device__ inline void atomAddF(float* p, float v) {
    __hip_atomic_fetch_add(p, v, __ATOMIC_RELAXED, __HIP_MEMORY_SCOPE_AGENT);
}

// ---------------- one-time conversion fp32 -> fp16 (W, P, WL fused) ----------------
__global__ __launch_bounds__(256) void cvt_all(const float* __restrict__ W, const float* __restrict__ P,
                                               const float* __restrict__ WL,
                                               unsigned short* __restrict__ Wb, unsigned short* __restrict__ Pb,
                                               unsigned short* __restrict__ WLb) {
    int i = blockIdx.x * 256 + threadIdx.x;
    const float* src; unsigned short* dst; int idx;
    if (i < 3145728)               { src = W;  dst = Wb;  idx = i; }
    else if (i < 3145728 + 4194304){ src = P;  dst = Pb;  idx = i - 3145728; }
    else                           { src = WL; dst = WLb; idx = i - (3145728 + 4194304); }
    float4 v = ((const float4*)src)[idx];
    us4v o;
    o[0] = f16b(v.x); o[1] = f16b(v.y); o[2] = f16b(v.z); o[3] = f16b(v.w);
    ((us4v*)dst)[idx] = o;
}

// P [2048][4096][2] f32  ->  PT [4096][4096] f16 where PT[m][n*2+p] = P[n][m][p]
__global__ __launch_bounds__(256) void transpose_p(const float* __restrict__ P,
                                                   unsigned short* __restrict__ PT) {
    __shared__ unsigned int lds[64][33];
    int bid = blockIdx.x;
    int m0 = (bid & 127) * 32;
    int n0 = (bid >> 7) * 64;
    int tid = threadIdx.x;
    const float2* P2 = (const float2*)P;
    #pragma unroll
    for (int it = 0; it < 8; ++it) {
        int idx = it * 256 + tid;
        int nl = idx >> 5, ml = idx & 31;
        float2 v = P2[(size_t)(n0 + nl) * 4096 + (m0 + ml)];
        unsigned int pk = (unsigned int)f16b(v.x) | ((unsigned int)f16b(v.y) << 16);
        lds[nl][ml] = pk;
    }
    __syncthreads();
    unsigned int* PTu = (unsigned int*)PT;
    #pragma unroll
    for (int it = 0; it < 8; ++it) {
        int idx = it * 256 + tid;
        int ml = idx >> 6, nl = idx & 63;
        PTu[(size_t)(m0 + ml) * 2048 + (n0 + nl)] = lds[nl][ml];
    }
}

// ---------------- per-layer B-matrix build, BN fused (fragment layout) ----------------
// Fragment layout: elem index ((t*2+h)*64+lane)*8+e holds B[k=t*32+(lane>>4)*8+e][g=h*16+(lane&15)]
__global__ __launch_bounds__(256) void build_b(
    const float* __restrict__ srcx, const float* __restrict__ srcy,
    int Fin, int Fout, int buildB2, int use_bn,
    const float* __restrict__ stats,
    const float* __restrict__ gx, const float* __restrict__ btx,
    const float* __restrict__ gy, const float* __restrict__ bty,
    const float* __restrict__ w1a, const float* __restrict__ w1b,
    const float* __restrict__ w2a, const float* __restrict__ w2b,
    unsigned short* __restrict__ B1f, unsigned short* __restrict__ B2f) {
    int tid0 = blockIdx.x * 256 + threadIdx.x;
    const int NB1 = 14336 * 32;
    int isB2 = 0, t2 = tid0;
    if (tid0 >= NB1) {
        if (!buildB2) return;
        isB2 = 1; t2 = tid0 - NB1;
        if (t2 >= 16384 * 32) return;
    }
    int e = t2 & 7, lane = (t2 >> 3) & 63, hh = (t2 >> 9) & 1, t = t2 >> 10;
    int k = (t << 5) | ((lane >> 4) << 3) | e;
    int g = (hh << 4) | (lane & 15);
    float v = 0.f;
    if (g < Fout) {
        const float* hr; const float* wc; int useY;
        if (!isB2) {
            if (k < 6144) { int m = k / 3, j = k - 3 * m; hr = srcx + m * Fin; wc = w1a + (j * Fin) * Fout + g; useY = 0; }
            else { int k2 = k - 6144; int m = k2 >> 1, p = k2 & 1; hr = srcy + m * Fin; wc = w1b + (p * Fin) * Fout + g; useY = 1; }
        } else {
            if (k < 12288) { int m = k / 3, j = k - 3 * m; hr = srcy + m * Fin; wc = w2a + (j * Fin) * Fout + g; useY = 1; }
            else { int k2 = k - 12288; int n = k2 >> 1, p = k2 & 1; hr = srcx + n * Fin; wc = w2b + (p * Fin) * Fout + g; useY = 0; }
        }
        float a = 0.f;
        if (use_bn) {
            const float* st = useY ? stats + 64 : stats;
            const float* gv = useY ? gy : gx;
            const float* bv = useY ? bty : btx;
            float invn = useY ? (1.f / 4096.f) : (1.f / 2048.f);
            #pragma unroll
            for (int f = 0; f < 32; ++f) {
                float mean = st[f] * invn;
                float var = st[32 + f] * invn - mean * mean;
                float sc = gv[f] * rsqrtf(var + 1e-5f);
                float h = sc * (hr[f] - mean) + bv[f];
                a += h * wc[f * Fout];
            }
        } else {
            for (int f = 0; f < Fin; ++f) a += hr[f] * wc[f * Fout];
        }
        v = a;
    }
    if (!isB2) B1f[t2] = f16b(v); else B2f[t2] = f16b(v);
}

// ---------------- split-K MFMA GEMM, 4-wave k-split per tile ----------------
// Tile = 32 rows x 1024 K per WG; wave w owns k-quarter [kb+256w, kb+256w+256).
// LDS tree-reduce of 4 quarter-accumulators, one partial write per tile.
// x-branch: 64 mwgs x 14 ksegs = 896 WGs (segs 0..5 = W, 6..13 = P)
// y-branch: 128 mwgs x 16 ksegs = 2048 WGs (segs 0..11 = WL, 12..15 = PT)
__global__ __launch_bounds__(256) void gemm_k(
    const unsigned short* __restrict__ Wb, const unsigned short* __restrict__ Pb,
    const unsigned short* __restrict__ WLb, const unsigned short* __restrict__ PTb,
    const unsigned short* __restrict__ B1f, const unsigned short* __restrict__ B2f,
    float* __restrict__ px, float* __restrict__ py, float* __restrict__ stats, int nwgx) {
    __shared__ float lds[4][1024];
    int bid = blockIdx.x;
    if (bid == 0 && threadIdx.x < 128) stats[threadIdx.x] = 0.f;  // pre-zero for next reduce
    const unsigned short* Bf;
    float* Z;
    int seg, Mbase, rowlen, kloc, kb;
    const unsigned short* A16;
    if (bid < nwgx) {
        Bf = B1f;
        int mwg = bid / 14; seg = bid % 14;
        Mbase = mwg * 32;
        kb = seg << 10;
        Z = px + (size_t)seg * 65536;
        if (seg < 6) { rowlen = 6144; kloc = kb;        A16 = Wb; }
        else         { rowlen = 8192; kloc = kb - 6144; A16 = Pb; }
    } else {
        int b2 = bid - nwgx;
        Bf = B2f;
        int mwg = b2 / 16; seg = b2 % 16;
        Mbase = mwg * 32;
        kb = seg << 10;
        Z = py + (size_t)seg * 131072;
        if (seg < 12) { rowlen = 12288; kloc = kb;         A16 = WLb; }
        else          { rowlen = 4096;  kloc = kb - 12288; A16 = PTb; }
    }
    int wid = threadIdx.x >> 6, lane = threadIdx.x & 63;
    int kq = wid << 8;  // this wave's 256-K quarter offset
    const unsigned short* ap0 = A16 + (size_t)(Mbase + (lane & 15)) * rowlen + kloc + kq + ((lane >> 4) << 3);
    const unsigned short* ap1 = ap0 + (size_t)16 * rowlen;
    const unsigned short* bp = Bf + ((size_t)((kb + kq) >> 5)) * 1024 + lane * 8;
    f32x4 acc00 = {0.f,0.f,0.f,0.f}, acc01 = {0.f,0.f,0.f,0.f};
    f32x4 acc10 = {0.f,0.f,0.f,0.f}, acc11 = {0.f,0.f,0.f,0.f};
    #pragma unroll
    for (int ks = 0; ks < 8; ++ks) {
        f16x8 a0 = *(const f16x8*)ap0;
        f16x8 a1 = *(const f16x8*)ap1;
        f16x8 b0 = *(const f16x8*)bp;
        f16x8 b1 = *(const f16x8*)(bp + 512);
        acc00 = __builtin_amdgcn_mfma_f32_16x16x32_f16(a0, b0, acc00, 0, 0, 0);
        acc10 = __builtin_amdgcn_mfma_f32_16x16x32_f16(a1, b0, acc10, 0, 0, 0);
        acc01 = __builtin_amdgcn_mfma_f32_16x16x32_f16(a0, b1, acc01, 0, 0, 0);
        acc11 = __builtin_amdgcn_mfma_f32_16x16x32_f16(a1, b1, acc11, 0, 0, 0);
        ap0 += 32; ap1 += 32; bp += 1024;
    }
    // stash quarter-accumulators: tile index = row*32 + col
    int col = lane & 15, r0 = (lane >> 4) << 2;
    float* l = lds[wid];
    #pragma unroll
    for (int r = 0; r < 4; ++r) {
        l[(r0 + r) * 32 + col]            = acc00[r];
        l[(r0 + r) * 32 + col + 16]       = acc01[r];
        l[(r0 + r + 16) * 32 + col]       = acc10[r];
        l[(r0 + r + 16) * 32 + col + 16]  = acc11[r];
    }
    __syncthreads();
    // 256 threads sum the 4 quarters, write one float4 each (coalesced 4 KB tile)
    int t = threadIdx.x;
    float4 a = ((const float4*)lds[0])[t];
    float4 b = ((const float4*)lds[1])[t];
    float4 c = ((const float4*)lds[2])[t];
    float4 d = ((const float4*)lds[3])[t];
    float4 s;
    s.x = (a.x + b.x) + (c.x + d.x);
    s.y = (a.y + b.y) + (c.y + d.y);
    s.z = (a.z + b.z) + (c.z + d.z);
    s.w = (a.w + b.w) + (c.w + d.w);
    ((float4*)(Z + (size_t)Mbase * 32))[t] = s;
}

// ---------------- reduce partials + bias + relu-half + column stats ----------------
// blocks 0..63: x (65536 elems), 64..191: y (131072 elems); each thread one float4
__global__ __launch_bounds__(256) void reduce_stats(
    const float* __restrict__ px, const float* __restrict__ py,
    const float* __restrict__ bx, const float* __restrict__ by,
    float* __restrict__ zax, float* __restrict__ zay,
    float* __restrict__ stats) {
    __shared__ float lsum[4][8][8];
    int bid = blockIdx.x, tid = threadIdx.x;
    const float4* src; const float* bias; float4* dst; float* st; int nseg, i4, stride4;
    if (bid < 64) { src = (const float4*)px; bias = bx; dst = (float4*)zax; st = stats;      nseg = 14; i4 = bid * 256 + tid;        stride4 = 16384; }
    else          { src = (const float4*)py; bias = by; dst = (float4*)zay; st = stats + 64; nseg = 16; i4 = (bid - 64) * 256 + tid; stride4 = 32768; }
    float4 s = {0.f, 0.f, 0.f, 0.f};
    for (int g = 0; g < nseg; ++g) {
        float4 v = src[(size_t)g * stride4 + i4];
        s.x += v.x; s.y += v.y; s.z += v.z; s.w += v.w;
    }
    int c0 = (i4 & 7) * 4;
    float4 b4 = *(const float4*)(bias + c0);
    s.x += b4.x; s.y += b4.y; s.z += b4.z; s.w += b4.w;
    if (c0 < 16) {
        s.x = fmaxf(s.x, 0.f); s.y = fmaxf(s.y, 0.f);
        s.z = fmaxf(s.z, 0.f); s.w = fmaxf(s.w, 0.f);
    }
    dst[i4] = s;
    float4 s2 = {s.x * s.x, s.y * s.y, s.z * s.z, s.w * s.w};
    #pragma unroll
    for (int mask = 8; mask <= 32; mask <<= 1) {
        s.x += __shfl_xor(s.x, mask); s.y += __shfl_xor(s.y, mask);
        s.z += __shfl_xor(s.z, mask); s.w += __shfl_xor(s.w, mask);
        s2.x += __shfl_xor(s2.x, mask); s2.y += __shfl_xor(s2.y, mask);
        s2.z += __shfl_xor(s2.z, mask); s2.w += __shfl_xor(s2.w, mask);
    }
    int w = tid >> 6, ln = tid & 63;
    if (ln < 8) {
        lsum[w][ln][0] = s.x;  lsum[w][ln][1] = s.y;  lsum[w][ln][2] = s.z;  lsum[w][ln][3] = s.w;
        lsum[w][ln][4] = s2.x; lsum[w][ln][5] = s2.y; lsum[w][ln][6] = s2.z; lsum[w][ln][7] = s2.w;
    }
    __syncthreads();
    if (tid < 64) {
        int q = tid >> 3, e = tid & 7;
        float v = lsum[0][q][e] + lsum[1][q][e] + lsum[2][q][e] + lsum[3][q][e];
        int col = q * 4 + (e & 3);
        atomAddF((e < 4) ? &st[col] : &st[32 + col], v);
    }
}

// ---------------- final: sum x-partials + bl -> out ----------------
__global__ __launch_bounds__(256) void out_final(const float* __restrict__ px,
                                                 const float* __restrict__ bl,
                                                 float* __restrict__ out) {
    int tid = blockIdx.x * 256 + threadIdx.x;
    if (tid < 4096) {
        int n = tid >> 1, c = tid & 1;
        float a = bl[c];
        for (int s = 0; s < 14; ++s) a += px[(size_t)s * 65536 + n * 32 + c];
        out[tid] = a;
    }
}

extern "C" void kernel_launch(void* const* d_in, const int* in_sizes, int n_in,
                              void* d_out, int out_size, void* d_ws, size_t ws_size,
                              hipStream_t stream) {
    const float* W    = (const float*)d_in[0];
    const float* x    = (const float*)d_in[1];
    const float* WL   = (const float*)d_in[2];
    const float* y    = (const float*)d_in[3];
    const float* P    = (const float*)d_in[4];
    const float* wx2x0 = (const float*)d_in[5];
    const float* wy2x0 = (const float*)d_in[6];
    const float* bx0   = (const float*)d_in[7];
    const float* wy2y0 = (const float*)d_in[8];
    const float* wx2y0 = (const float*)d_in[9];
    const float* by0   = (const float*)d_in[10];
    const float* gx0   = (const float*)d_in[11];
    const float* btx0  = (const float*)d_in[12];
    const float* gy0   = (const float*)d_in[13];
    const float* bty0  = (const float*)d_in[14];
    const float* wx2x_m = (const float*)d_in[15];
    const float* wy2x_m = (const float*)d_in[16];
    const float* bx_m   = (const float*)d_in[17];
    const float* wy2y_m = (const float*)d_in[18];
    const float* wx2y_m = (const float*)d_in[19];
    const float* by_m   = (const float*)d_in[20];
    const float* gx_m   = (const float*)d_in[21];
    const float* btx_m  = (const float*)d_in[22];
    const float* gy_m   = (const float*)d_in[23];
    const float* bty_m  = (const float*)d_in[24];
    const float* wlx = (const float*)d_in[25];
    const float* wly = (const float*)d_in[26];
    const float* bl  = (const float*)d_in[27];

    char* base = (char*)d_ws;
    unsigned short* Wb  = (unsigned short*)(base + 0);          // 25,165,824 B
    unsigned short* Pb  = (unsigned short*)(base + 25165824);   // 33,554,432 B
    unsigned short* WLb = (unsigned short*)(base + 58720256);   // 100,663,296 B
    unsigned short* PTb = (unsigned short*)(base + 159383552);  // 33,554,432 B
    unsigned short* B1f = (unsigned short*)(base + 192937984);  // 917,504 B
    unsigned short* B2f = (unsigned short*)(base + 193855488);  // 1,048,576 B
    float* zax   = (float*)(base + 194904064);  // 262,144 B
    float* zay   = (float*)(base + 195166208);  // 524,288 B
    float* stats = (float*)(base + 195690496);  // 512 B
    float* px    = (float*)(base + 195691008);  // 14*65536*4  = 3,670,016 B
    float* py    = (float*)(base + 199361024);  // 16*131072*4 = 8,388,608 B

    // one-time conversions
    cvt_all<<<77824, 256, 0, stream>>>(W, P, WL, Wb, Pb, WLb);
    transpose_p<<<4096, 256, 0, stream>>>(P, PTb);

    // block 0 (Fin = 1, raw x/y, no bn)
    build_b<<<3840, 256, 0, stream>>>(x, y, 1, 32, 1, 0, nullptr, nullptr, nullptr, nullptr, nullptr,
                                      wx2x0, wy2x0, wy2y0, wx2y0, B1f, B2f);
    gemm_k<<<2944, 256, 0, stream>>>(Wb, Pb, WLb, PTb, B1f, B2f, px, py, stats, 896);
    reduce_stats<<<192, 256, 0, stream>>>(px, py, bx0, by0, zax, zay, stats);

    // blocks 1..6 (middle weights i = 0..5); bn params of block i come from previous block
    for (int i = 0; i < 6; ++i) {
        const float* gv  = (i == 0) ? gx0  : gx_m  + (i - 1) * 32;
        const float* bv  = (i == 0) ? btx0 : btx_m + (i - 1) * 32;
        const float* gvy = (i == 0) ? gy0  : gy_m  + (i - 1) * 32;
        const float* bvy = (i == 0) ? bty0 : bty_m + (i - 1) * 32;
        build_b<<<3840, 256, 0, stream>>>(zax, zay, 32, 32, 1, 1, stats, gv, bv, gvy, bvy,
                                          wx2x_m + i * 3072, wy2x_m + i * 2048,
                                          wy2y_m + i * 3072, wx2y_m + i * 2048, B1f, B2f);
        gemm_k<<<2944, 256, 0, stream>>>(Wb, Pb, WLb, PTb, B1f, B2f, px, py, stats, 896);
        reduce_stats<<<192, 256, 0, stream>>>(px, py, bx_m + i * 32, by_m + i * 32, zax, zay, stats);
    }

    // final layer: bn of block 6 (gx_m[5]...), linear weights, x-branch only
    build_b<<<1792, 256, 0, stream>>>(zax, zay, 32, 2, 0, 1, stats,
                                      gx_m + 5 * 32, btx_m + 5 * 32, gy_m + 5 * 32, bty_m + 5 * 32,
                                      wlx, wly, nullptr, nullptr, B1f, B2f);
    gemm_k<<<896, 256, 0, stream>>>(Wb, Pb, WLb, PTb, B1f, B2f, px, py, stats, 896);
    out_final<<<16, 256, 0, stream>>>(px, bl, (float*)d_out);
}